// Round 10
// baseline (709.532 us; speedup 1.0000x reference)
//
#include <hip/hip_runtime.h>
#include <cstdint>
#include <cstddef>

// Problem constants (fixed by the reference)
#define NN 50000
#define EE 400000
#define FIN 128
#define HH 3
#define DD 64
#define GG 64
#define PP 64
#define HD 192   // H*D
#define EBL 1563 // (EE+255)/256

typedef short bf16x8 __attribute__((ext_vector_type(8)));   // 8 bf16 (4 VGPRs)
typedef float f32x4 __attribute__((ext_vector_type(4)));
typedef unsigned int u32x2 __attribute__((ext_vector_type(2)));

__device__ inline int wsumi(int v) {
#pragma unroll
    for (int m = 32; m > 0; m >>= 1) v += __shfl_xor(v, m, 64);
    return v;
}

// bf16 <-> f32 (RNE)
__device__ inline float bf2f(unsigned short u) {
    union { unsigned int i; float f; } x; x.i = ((unsigned int)u) << 16; return x.f;
}
__device__ inline unsigned short f2bf(float f) {
    union { float f; unsigned int i; } x; x.f = f;
    unsigned int r = x.i + 0x7FFFu + ((x.i >> 16) & 1u);
    return (unsigned short)(r >> 16);
}

// unpack one dword = 2 packed bf16 -> 2 floats
__device__ inline void unp2(unsigned int w, float& lo, float& hi) {
    union { unsigned int i; float f; } x;
    x.i = w << 16;          lo = x.f;
    x.i = w & 0xFFFF0000u;  hi = x.f;
}
// load 4 consecutive bf16 (8B aligned) -> 4 floats
__device__ inline void load4(const unsigned short* p, float* o) {
    u32x2 w = *(const u32x2*)p;
    unp2(w[0], o[0], o[1]);
    unp2(w[1], o[2], o[3]);
}

// load one FS row segment (3 heads x 4 consecutive features at col)
__device__ inline void loadrow(const unsigned short* __restrict__ FS, int u, int col,
                               float f[3][4]) {
    size_t bu = (size_t)u * HD + col;
#pragma unroll
    for (int h = 0; h < 3; h++) load4(&FS[bu + h * 64], f[h]);
}

// ---------------- weight pre-pack helper ----------------
__device__ inline void pack_one(const float* __restrict__ W, unsigned short* __restrict__ WP,
                                int id, int Kc) {
    int lane = id & 63;
    int kc = (id >> 6) % Kc;
    int ct = (id >> 6) / Kc;
    int n = ct * 16 + (lane & 15);
    int kb = kc * 32 + (lane >> 4) * 8;
#pragma unroll
    for (int j = 0; j < 8; j++)
        WP[(unsigned)id * 8 + j] = f2bf(W[(unsigned)(kb + j) * HD + n]);
}

#define IDS128 (12 * 4 * 64)   // 3072
#define IDS192 (12 * 6 * 64)   // 4608

// ---------------- fused: edge-count (CSR) + weight pre-pack, one dispatch ------
__global__ void k_count_pack(const int* __restrict__ dst, int* __restrict__ counts,
                             const float* W1s, const float* W1d,
                             const float* W2s, const float* W2d,
                             const float* W3s, const float* W3d,
                             unsigned short* P1s, unsigned short* P1d,
                             unsigned short* P2s, unsigned short* P2d,
                             unsigned short* P3s, unsigned short* P3d) {
    int b = blockIdx.x;
    if (b < EBL) {
        int e = b * 256 + threadIdx.x;
        if (e < EE) atomicAdd(&counts[dst[e]], 1);
        return;
    }
    int idx = (b - EBL) * 256 + threadIdx.x;
    if (idx < IDS128) { pack_one(W1s, P1s, idx, 4); return; }
    idx -= IDS128;
    if (idx < IDS128) { pack_one(W1d, P1d, idx, 4); return; }
    idx -= IDS128;
    if (idx < IDS192) { pack_one(W2s, P2s, idx, 6); return; }
    idx -= IDS192;
    if (idx < IDS192) { pack_one(W2d, P2d, idx, 6); return; }
    idx -= IDS192;
    if (idx < IDS192) { pack_one(W3s, P3s, idx, 6); return; }
    idx -= IDS192;
    if (idx < IDS192) { pack_one(W3d, P3d, idx, 6); return; }
}

// ---------------- degree-bucket permutation (R26) ----------------
// Waves in k_node_gat pay max(deg of 4 groups) per loop instruction; for
// Poisson(8) that's E[max4]~11.5 vs mean 8 (44% divergence tax). Counting-sort
// nodes by degree (64 bins) so the 4 groups of a wave have ~equal degrees.
__global__ void k_dhist(const int* __restrict__ counts, int* __restrict__ dhist) {
    int i = blockIdx.x * 256 + threadIdx.x;
    if (i < NN) {
        int b = counts[i]; if (b > 63) b = 63;
        atomicAdd(&dhist[b], 1);
    }
}

__global__ void k_dperm(const int* __restrict__ counts, const int* __restrict__ dhist,
                        int* __restrict__ dcur, int* __restrict__ perm) {
    __shared__ int sbase[64];
    int tid = threadIdx.x;
    if (tid < 64) {
        int x = dhist[tid];
        int s = x;
#pragma unroll
        for (int d = 1; d < 64; d <<= 1) {
            int t = __shfl_up(s, d, 64);
            if (tid >= d) s += t;
        }
        sbase[tid] = s - x;                 // exclusive prefix of bin sizes
    }
    __syncthreads();
    int i = blockIdx.x * 256 + tid;
    if (i < NN) {
        int b = counts[i]; if (b > 63) b = 63;
        int pos = sbase[b] + atomicAdd(&dcur[b], 1);
        perm[pos] = i;
    }
}

// ---------------- block scan: wave-shuffle version ----------------
__global__ void k_scan_block(const int* __restrict__ in, int* __restrict__ out,
                             int* __restrict__ bsums) {
    int tid = threadIdx.x;
    int lane = tid & 63, w = tid >> 6;          // 16 waves
    int i = blockIdx.x * 1024 + tid;
    int v = (i < NN) ? in[i] : 0;
    int s = v;
#pragma unroll
    for (int d = 1; d < 64; d <<= 1) {
        int t = __shfl_up(s, d, 64);
        if (lane >= d) s += t;                  // s = inclusive wave scan
    }
    __shared__ int wsum[16], wpre[16];
    if (lane == 63) wsum[w] = s;
    __syncthreads();
    if (w == 0 && lane < 16) {
        int x = wsum[lane];
#pragma unroll
        for (int d = 1; d < 16; d <<= 1) {
            int t = __shfl_up(x, d, 64);
            if (lane >= d) x += t;
        }
        wpre[lane] = x - wsum[lane];            // exclusive prefix of wave sums
        if (lane == 15) bsums[blockIdx.x] = x;  // block total
    }
    __syncthreads();
    if (i < NN) out[i] = s - v + wpre[w];       // exclusive scan
}

// fused: each block computes its own bsums-prefix (nb <= 64) then adds it
__global__ void k_scan_add(int* __restrict__ row_ptr, const int* __restrict__ bsums, int nb) {
    __shared__ int sbase;
    int tid = threadIdx.x;
    if (tid < 64) {
        int v = (tid < blockIdx.x) ? bsums[tid] : 0;   // blockIdx.x <= nb <= 64
        v = wsumi(v);
        if (tid == 0) sbase = v;
    }
    __syncthreads();
    int i = blockIdx.x * 1024 + tid;
    if (i < NN) row_ptr[i] += sbase;
    else if (i == NN) row_ptr[NN] = EE;   // sentinel for node-centric kernel
}

__global__ void k_scatter(const int* __restrict__ src, const int* __restrict__ dst,
                          const int* __restrict__ row_ptr, int* __restrict__ cursor,
                          int* __restrict__ csr_src) {
    int e = blockIdx.x * 256 + threadIdx.x;
    if (e >= EE) return;
    int v = dst[e];
    int pos = row_ptr[v] + atomicAdd(&cursor[v], 1);
    csr_src[pos] = src[e];
}

// ---------------- MFMA GEMM: [N,K]@[K,192] x2 (Ws,Wd); outputs bf16 ------------
// R25 two-pass slim build (kept from R9). Epilogue keeps the LDS transpose
// (R6/R7 rule: HBM writeback clean only with >=128B adjacent-lane runs).
template <int K, bool BF16IN>
__global__ __launch_bounds__(256, 4) void k_gemm_mfma(const void* __restrict__ Xin,
                                                      const unsigned short* __restrict__ WPs,
                                                      const unsigned short* __restrict__ WPd,
                                                      unsigned short* __restrict__ FS,
                                                      unsigned short* __restrict__ FD) {
    constexpr int Kc = K / 32;
    constexpr int XW = K + 8;                      // xs row width (shorts)
    constexpr int BW = (XW > 200) ? XW : 200;      // union width (200 for K<=192)
    __shared__ unsigned short smem[64 * BW];       // 25.6 KB
    unsigned short (*xs)[XW]  = (unsigned short (*)[XW])smem;
    unsigned short (*cs)[200] = (unsigned short (*)[200])smem;
    int tid = threadIdx.x;
    int row0 = blockIdx.x * 64;
    int lane = tid & 63, wv = tid >> 6;
    int m = lane & 15, quad = lane >> 4;

    const unsigned short* WPx[2] = {WPs, WPd};
    unsigned short* OUTx[2] = {FS, FD};

    for (int half = 0; half < 2; half++) {
        // ---- stage X tile (re-staged on pass 1; L2-hot) ----
        if (BF16IN) {
            const unsigned short* XB = (const unsigned short*)Xin;
            for (int c = tid; c < 64 * K / 8; c += 256) {
                int r = c / (K / 8), kk = (c - r * (K / 8)) * 8;
                int row = row0 + r; if (row > NN - 1) row = NN - 1;   // clamp (loads only)
                *(bf16x8*)&xs[r][kk] = *(const bf16x8*)&XB[(unsigned)(row * K + kk)];
            }
        } else {
            const float* X = (const float*)Xin;
            for (int c = tid; c < 64 * K / 4; c += 256) {
                int r = c / (K / 4), k4 = (c - r * (K / 4)) * 4;
                int row = row0 + r; if (row > NN - 1) row = NN - 1;
                f32x4 v = *(const f32x4*)&X[(unsigned)(row * K + k4)];
                xs[r][k4 + 0] = f2bf(v[0]);
                xs[r][k4 + 1] = f2bf(v[1]);
                xs[r][k4 + 2] = f2bf(v[2]);
                xs[r][k4 + 3] = f2bf(v[3]);
            }
        }
        __syncthreads();

        // ---- kc loop: this pass's 12 column-tiles (3 per wave) ----
        f32x4 acc[4][3];
#pragma unroll
        for (int s = 0; s < 4; s++)
#pragma unroll
            for (int t = 0; t < 3; t++) acc[s][t] = (f32x4){0.f, 0.f, 0.f, 0.f};

        const unsigned short* wp = WPx[half];
        for (int kc = 0; kc < Kc; kc++) {
            bf16x8 b[3];
#pragma unroll
            for (int t = 0; t < 3; t++) {
                int c = wv * 3 + t;                // 0..11
                b[t] = *(const bf16x8*)&wp[(unsigned)(((c * Kc + kc) * 64 + lane) * 8)];
            }
#pragma unroll
            for (int s = 0; s < 4; s++) {
                bf16x8 a = *(const bf16x8*)&xs[s * 16 + m][kc * 32 + quad * 8];
#pragma unroll
                for (int t = 0; t < 3; t++)
                    acc[s][t] = __builtin_amdgcn_mfma_f32_16x16x32_bf16(a, b[t], acc[s][t], 0, 0, 0);
            }
        }
        __syncthreads();    // xs reads done before cs overwrite (shared buffer)

        // ---- LDS transpose + vector store (192 cols of this pass's matrix) ----
#pragma unroll
        for (int s = 0; s < 4; s++)
#pragma unroll
            for (int t = 0; t < 3; t++) {
                int ct = wv * 3 + t;
#pragma unroll
                for (int r = 0; r < 4; r++)
                    cs[s * 16 + quad * 4 + r][ct * 16 + m] = f2bf(acc[s][t][r]);
            }
        __syncthreads();
        unsigned short* OUT = OUTx[half];
#pragma unroll
        for (int it = 0; it < 6; it++) {
            int c = tid + it * 256;                // 0..1535
            int row = c / 24, ch = c - row * 24;
            int grow = row0 + row;
            if (grow < NN)
                *(bf16x8*)&OUT[(unsigned)(grow * HD + ch * 8)] =
                    *(const bf16x8*)&cs[row][ch * 8];
        }
        __syncthreads();    // cs reads done before next pass's stage overwrites
    }
}

// ---------------- node-centric GATv2 (CSR), 16-lane group per node -------------
// R26: R20 structure + degree-sorted node order via perm[] (groups in a wave
// get ~equal degrees -> divergence tax max4/mean ~1.44x -> ~1.0x).
// FINAL=false: store finalized bf16 next-GEMM input (r/den + bias), [NN][192].
// FINAL=true : store head-mean (1/3 * sum_h (r/den + bias)) f32, [NN][64].
template <bool FINAL>
__global__ __launch_bounds__(256) void k_node_gat(const int* __restrict__ perm,
                                                  const int* __restrict__ row_ptr,
                                                  const int* __restrict__ csr_src,
                                                  const unsigned short* __restrict__ FS,
                                                  const unsigned short* __restrict__ FD,
                                                  const float* __restrict__ A,
                                                  const float* __restrict__ Bv,
                                                  unsigned short* __restrict__ XB,
                                                  float* __restrict__ H64) {
    int tid = threadIdx.x;
    int grp = tid >> 4, sub = tid & 15;         // 16 groups per block
    int node = perm[blockIdx.x * 16 + grp];     // degree-sorted order
    int col = sub * 4;

    float a[3][4];
#pragma unroll
    for (int h = 0; h < 3; h++) {
        f32x4 av = *(const f32x4*)&A[h * 64 + col];
#pragma unroll
        for (int j = 0; j < 4; j++) a[h][j] = av[j];
    }

    int lo = row_ptr[node], hi = row_ptr[node + 1];

    float g[3][4];
#pragma unroll
    for (int h = 0; h < 3; h++) load4(&FD[(size_t)node * HD + h * 64 + col], g[h]);

    float r[3][4];
#pragma unroll
    for (int h = 0; h < 3; h++)
#pragma unroll
        for (int j = 0; j < 4; j++) r[h][j] = 0.f;
    float d0 = 0.f, d1 = 0.f, d2 = 0.f;

    auto accum = [&](const float f[3][4]) {
        float p0 = 0.f, p1 = 0.f, p2 = 0.f;
#pragma unroll
        for (int j = 0; j < 4; j++) {
            float s0 = f[0][j] + g[0][j]; s0 = fmaxf(s0, 0.2f * s0); p0 += s0 * a[0][j];
            float s1 = f[1][j] + g[1][j]; s1 = fmaxf(s1, 0.2f * s1); p1 += s1 * a[1][j];
            float s2 = f[2][j] + g[2][j]; s2 = fmaxf(s2, 0.2f * s2); p2 += s2 * a[2][j];
        }
        // 4-step butterfly within the 16-lane group (masks < 16 stay in-group)
#pragma unroll
        for (int m = 8; m > 0; m >>= 1) {
            p0 += __shfl_xor(p0, m, 64);
            p1 += __shfl_xor(p1, m, 64);
            p2 += __shfl_xor(p2, m, 64);
        }
        float w0 = __expf(p0), w1 = __expf(p1), w2 = __expf(p2);
#pragma unroll
        for (int j = 0; j < 4; j++) {
            r[0][j] += w0 * f[0][j];
            r[1][j] += w1 * f[1][j];
            r[2][j] += w2 * f[2][j];
        }
        d0 += w0; d1 += w1; d2 += w2;
    };

    if (hi > lo) {
        int last = hi - 1;
        float fA[3][4], fB[3][4], fC[3][4];
        loadrow(FS, csr_src[lo], col, fA);
        loadrow(FS, csr_src[lo + 1 <= last ? lo + 1 : last], col, fB);
        for (int e = lo; e < hi; e += 3) {
            // prefetch the index stream for this step up front (independent loads)
            int eC = e + 2 <= last ? e + 2 : last;
            int eA = e + 3 <= last ? e + 3 : last;
            int eB = e + 4 <= last ? e + 4 : last;
            int uC = csr_src[eC], uA = csr_src[eA], uB = csr_src[eB];
            loadrow(FS, uC, col, fC);      // in flight during accum(fA), accum(fB)
            accum(fA);                     // edge e (always valid inside loop)
            loadrow(FS, uA, col, fA);      // for e+3, in flight 2 phases
            if (e + 1 < hi) accum(fB);
            loadrow(FS, uB, col, fB);      // for e+4, in flight 2 phases
            if (e + 2 < hi) accum(fC);
        }
    }

    float b[3][4];
#pragma unroll
    for (int h = 0; h < 3; h++) {
        f32x4 bv = *(const f32x4*)&Bv[h * 64 + col];
#pragma unroll
        for (int j = 0; j < 4; j++) b[h][j] = bv[j];
    }

    float q0 = fmaxf(d0, 1e-9f), q1 = fmaxf(d1, 1e-9f), q2 = fmaxf(d2, 1e-9f);
    if (FINAL) {
        f32x4 m;
#pragma unroll
        for (int j = 0; j < 4; j++)
            m[j] = (r[0][j] / q0 + b[0][j] + r[1][j] / q1 + b[1][j] +
                    r[2][j] / q2 + b[2][j]) * (1.f / 3.f);
        *(f32x4*)&H64[(size_t)node * 64 + col] = m;
    } else {
        float qq[3] = {q0, q1, q2};
#pragma unroll
        for (int h = 0; h < 3; h++) {
            unsigned short o0 = f2bf(r[h][0] / qq[h] + b[h][0]);
            unsigned short o1 = f2bf(r[h][1] / qq[h] + b[h][1]);
            unsigned short o2 = f2bf(r[h][2] / qq[h] + b[h][2]);
            unsigned short o3 = f2bf(r[h][3] / qq[h] + b[h][3]);
            u32x2 w;
            w[0] = (unsigned)o0 | ((unsigned)o1 << 16);
            w[1] = (unsigned)o2 | ((unsigned)o3 << 16);
            *(u32x2*)&XB[(size_t)node * HD + h * 64 + col] = w;
        }
    }
}

// ---------------- final: per-graph mean (256 blocks = 4 per graph) -------------
// Layer-3 output H64 is already finalized (den, bias, head-mean applied).
__global__ __launch_bounds__(256) void k_graph_mean(const float* __restrict__ H64,
                                                    const int* __restrict__ gids,
                                                    float* __restrict__ gsum,
                                                    int* __restrict__ gcnt) {
    int g = blockIdx.x >> 2, q = blockIdx.x & 3;
    int lo, hi;
    {
        int a = 0, b = NN;
        while (a < b) { int m = (a + b) >> 1; if (gids[m] < g) a = m + 1; else b = m; }
        lo = a;
        b = NN;
        while (a < b) { int m = (a + b) >> 1; if (gids[m] < g + 1) a = m + 1; else b = m; }
        hi = a;
    }
    int len = hi - lo;
    int qlen = (len + 3) >> 2;
    int s = lo + q * qlen;
    int e = s + qlen; if (e > hi) e = hi;
    int lane = threadIdx.x & 63, wv = threadIdx.x >> 6;

    float acc = 0.f;
    for (int v = s + wv; v < e; v += 4)
        acc += H64[(size_t)v * 64 + lane];
    __shared__ float red[4][64];
    red[wv][lane] = acc;
    __syncthreads();
    if (wv == 0) {
        float t = red[0][lane] + red[1][lane] + red[2][lane] + red[3][lane];
        if (e > s) {
            atomicAdd(&gsum[g * 64 + lane], t);
            if (lane == 0) atomicAdd(&gcnt[g], e - s);
        }
    }
}

// ---------------- head: one block PER GRAPH (64 blocks) ----------------
__global__ __launch_bounds__(128) void k_head(const float* __restrict__ gsum, const int* __restrict__ gcnt,
                                              const float* __restrict__ p1, const float* __restrict__ p2,
                                              const float* __restrict__ p3,
                                              const float* __restrict__ Wex, const float* __restrict__ bex,
                                              const float* __restrict__ Wpat, const float* __restrict__ bpat,
                                              const float* __restrict__ Wc1, const float* __restrict__ bc1,
                                              const float* __restrict__ Wc2, const float* __restrict__ bc2,
                                              const float* __restrict__ Wc3, const float* __restrict__ bc3,
                                              float* __restrict__ out) {
    int g = blockIdx.x;
    int tid = threadIdx.x;
    __shared__ float pbuf[192];   // p1|p2|p3 row for this graph
    __shared__ float ex[96], xc[128], t1[64], t2[32];

    if (tid < 64)       pbuf[tid] = p1[g * 64 + tid];
    else if (tid < 128) pbuf[tid] = p2[g * 64 + tid - 64];
    if (tid < 64)       pbuf[128 + tid] = p3[g * 64 + tid];
    if (tid >= 64 && tid < 128)
        xc[tid - 64] = gsum[g * 64 + tid - 64] / fmaxf((float)gcnt[g], 1.f);
    __syncthreads();
    if (tid < 96) {
        int jj = tid & 31;
        const float* pp = &pbuf[(tid >> 5) * 64];
        float acc = bex[jj];
        for (int k = 0; k < 64; k++) acc += pp[k] * Wex[k * 32 + jj];
        ex[tid] = acc;
    }
    __syncthreads();
    if (tid < 64) {
        float acc = bpat[tid];
        for (int k = 0; k < 96; k++) acc += ex[k] * Wpat[k * 64 + tid];
        xc[64 + tid] = acc > 0.f ? acc : 0.01f * acc;
    }
    __syncthreads();
    if (tid < 64) {
        float acc = bc1[tid];
        for (int k = 0; k < 128; k++) acc += xc[k] * Wc1[k * 64 + tid];
        t1[tid] = acc > 0.f ? acc : 0.01f * acc;
    }
    __syncthreads();
    if (tid < 32) {
        float acc = bc2[tid];
        for (int k = 0; k < 64; k++) acc += t1[k] * Wc2[k * 32 + tid];
        t2[tid] = acc > 0.f ? acc : 0.01f * acc;
    }
    __syncthreads();
    if (tid < 2) {
        float acc = bc3[tid];
        for (int k = 0; k < 32; k++) acc += t2[k] * Wc3[k * 2 + tid];
        out[g * 2 + tid] = acc;
    }
}

extern "C" void kernel_launch(void* const* d_in, const int* in_sizes, int n_in,
                              void* d_out, int out_size, void* d_ws, size_t ws_size,
                              hipStream_t stream) {
    const float* X0  = (const float*)d_in[0];
    const int*   src = (const int*)d_in[1];
    const int*   dst = (const int*)d_in[2];
    const int*   gid = (const int*)d_in[3];
    const float* p1  = (const float*)d_in[4];
    const float* p2  = (const float*)d_in[5];
    const float* p3  = (const float*)d_in[6];
    const float* W1s = (const float*)d_in[7],  *W1d = (const float*)d_in[8];
    const float* a1  = (const float*)d_in[9],  *b1  = (const float*)d_in[10];
    const float* W2s = (const float*)d_in[11], *W2d = (const float*)d_in[12];
    const float* a2  = (const float*)d_in[13], *b2  = (const float*)d_in[14];
    const float* W3s = (const float*)d_in[15], *W3d = (const float*)d_in[16];
    const float* a3  = (const float*)d_in[17], *b3  = (const float*)d_in[18];
    const float* Wex = (const float*)d_in[19], *bex = (const float*)d_in[20];
    const float* Wpat= (const float*)d_in[21], *bpat= (const float*)d_in[22];
    const float* Wc1 = (const float*)d_in[23], *bc1 = (const float*)d_in[24];
    const float* Wc2 = (const float*)d_in[25], *bc2 = (const float*)d_in[26];
    const float* Wc3 = (const float*)d_in[27], *bc3 = (const float*)d_in[28];
    float* out = (float*)d_out;

    char* ws = (char*)d_ws;
    size_t off = 0;
    auto alloc = [&](size_t bytes) -> char* {
        char* p = ws + off;
        off = (off + bytes + 255) & ~(size_t)255;
        return p;
    };
    unsigned short* FS = (unsigned short*)alloc((size_t)NN * HD * 2);  // bf16
    unsigned short* FD = (unsigned short*)alloc((size_t)NN * HD * 2);  // bf16
    unsigned short* XB = (unsigned short*)alloc((size_t)NN * HD * 2);  // bf16 inter-layer
    float*          H64= (float*)alloc((size_t)NN * 64 * 4);           // layer-3 head-mean
    unsigned short* P1s = (unsigned short*)alloc((size_t)192 * 192 * 2);
    unsigned short* P1d = (unsigned short*)alloc((size_t)192 * 192 * 2);
    unsigned short* P2s = (unsigned short*)alloc((size_t)192 * 192 * 2);
    unsigned short* P2d = (unsigned short*)alloc((size_t)192 * 192 * 2);
    unsigned short* P3s = (unsigned short*)alloc((size_t)192 * 192 * 2);
    unsigned short* P3d = (unsigned short*)alloc((size_t)192 * 192 * 2);
    int* row_ptr = (int*)alloc((size_t)(NN + 1) * 4);
    int* csr_src = (int*)alloc((size_t)EE * 4);
    int* bsums   = (int*)alloc(64 * 4);
    int* perm    = (int*)alloc((size_t)NN * 4);
    // zeroed region (ONE memset): counts | cursor | dhist | dcur | gsum | gcnt
    char* zbase = ws + off;
    int*   counts = (int*)alloc((size_t)NN * 4);
    int*   cursor = (int*)alloc((size_t)NN * 4);
    int*   dhist  = (int*)alloc(64 * 4);
    int*   dcur   = (int*)alloc(64 * 4);
    float* gsum   = (float*)alloc((size_t)GG * 64 * 4);
    int*   gcnt   = (int*)alloc((size_t)GG * 4);
    size_t zbytes = (size_t)((ws + off) - zbase);

    hipMemsetAsync(zbase, 0, zbytes, stream);

    int nb  = (NN + 1023) / 1024;
    int nbl = (NN + 255) / 256;         // 196
    {
        int packbl = (2 * IDS128 + 4 * IDS192 + 255) / 256;   // 96
        k_count_pack<<<EBL + packbl, 256, 0, stream>>>(dst, counts,
                                                       W1s, W1d, W2s, W2d, W3s, W3d,
                                                       P1s, P1d, P2s, P2d, P3s, P3d);
    }
    k_scan_block<<<nb, 1024, 0, stream>>>(counts, row_ptr, bsums);
    k_scan_add<<<nb, 1024, 0, stream>>>(row_ptr, bsums, nb);
    k_dhist<<<nbl, 256, 0, stream>>>(counts, dhist);
    k_scatter<<<EBL, 256, 0, stream>>>(src, dst, row_ptr, cursor, csr_src);
    k_dperm<<<nbl, 256, 0, stream>>>(counts, dhist, dcur, perm);

    int gblk = (NN + 63) / 64;          // 782 blocks, 64 rows each
    int nblk = NN / 16;                 // 3125 node blocks (16 groups each)

    // layer 1 (K = 128, float input)
    k_gemm_mfma<128, false><<<gblk, 256, 0, stream>>>(X0, P1s, P1d, FS, FD);
    k_node_gat<false><<<nblk, 256, 0, stream>>>(perm, row_ptr, csr_src, FS, FD, a1, b1, XB, nullptr);
    // layer 2 (K = 192, bf16 finalized input)
    k_gemm_mfma<192, true><<<gblk, 256, 0, stream>>>(XB, P2s, P2d, FS, FD);
    k_node_gat<false><<<nblk, 256, 0, stream>>>(perm, row_ptr, csr_src, FS, FD, a2, b2, XB, nullptr);
    // layer 3 (K = 192, bf16 finalized input)
    k_gemm_mfma<192, true><<<gblk, 256, 0, stream>>>(XB, P3s, P3d, FS, FD);
    k_node_gat<true><<<nblk, 256, 0, stream>>>(perm, row_ptr, csr_src, FS, FD, a3, b3, nullptr, H64);

    // per-graph mean (256 blocks) then head (64 blocks)
    k_graph_mean<<<GG * 4, 256, 0, stream>>>(H64, gid, gsum, gcnt);
    k_head<<<GG, 128, 0, stream>>>(gsum, gcnt, p1, p2, p3, Wex, bex, Wpat, bpat,
                                   Wc1, bc1, Wc2, bc2, Wc3, bc3, out);
}

// Round 11
// 367.108 us; speedup vs baseline: 1.9328x; 1.9328x over previous
//
#include <hip/hip_runtime.h>
#include <cstdint>
#include <cstddef>

// Problem constants (fixed by the reference)
#define NN 50000
#define EE 400000
#define FIN 128
#define HH 3
#define DD 64
#define GG 64
#define PP 64
#define HD 192   // H*D
#define EBL 1563 // (EE+255)/256

typedef short bf16x8 __attribute__((ext_vector_type(8)));   // 8 bf16 (4 VGPRs)
typedef float f32x4 __attribute__((ext_vector_type(4)));
typedef unsigned int u32x2 __attribute__((ext_vector_type(2)));

__device__ inline int wsumi(int v) {
#pragma unroll
    for (int m = 32; m > 0; m >>= 1) v += __shfl_xor(v, m, 64);
    return v;
}

// bf16 <-> f32 (RNE)
__device__ inline float bf2f(unsigned short u) {
    union { unsigned int i; float f; } x; x.i = ((unsigned int)u) << 16; return x.f;
}
__device__ inline unsigned short f2bf(float f) {
    union { float f; unsigned int i; } x; x.f = f;
    unsigned int r = x.i + 0x7FFFu + ((x.i >> 16) & 1u);
    return (unsigned short)(r >> 16);
}

// unpack one dword = 2 packed bf16 -> 2 floats
__device__ inline void unp2(unsigned int w, float& lo, float& hi) {
    union { unsigned int i; float f; } x;
    x.i = w << 16;          lo = x.f;
    x.i = w & 0xFFFF0000u;  hi = x.f;
}
// load 4 consecutive bf16 (8B aligned) -> 4 floats
__device__ inline void load4(const unsigned short* p, float* o) {
    u32x2 w = *(const u32x2*)p;
    unp2(w[0], o[0], o[1]);
    unp2(w[1], o[2], o[3]);
}

// load one FS row segment (3 heads x 4 consecutive features at col)
__device__ inline void loadrow(const unsigned short* __restrict__ FS, int u, int col,
                               float f[3][4]) {
    size_t bu = (size_t)u * HD + col;
#pragma unroll
    for (int h = 0; h < 3; h++) load4(&FS[bu + h * 64], f[h]);
}

// ---------------- weight pre-pack helper ----------------
__device__ inline void pack_one(const float* __restrict__ W, unsigned short* __restrict__ WP,
                                int id, int Kc) {
    int lane = id & 63;
    int kc = (id >> 6) % Kc;
    int ct = (id >> 6) / Kc;
    int n = ct * 16 + (lane & 15);
    int kb = kc * 32 + (lane >> 4) * 8;
#pragma unroll
    for (int j = 0; j < 8; j++)
        WP[(unsigned)id * 8 + j] = f2bf(W[(unsigned)(kb + j) * HD + n]);
}

#define IDS128 (12 * 4 * 64)   // 3072
#define IDS192 (12 * 6 * 64)   // 4608

// ---------------- fused: edge-count (CSR) + weight pre-pack, one dispatch ------
__global__ void k_count_pack(const int* __restrict__ dst, int* __restrict__ counts,
                             const float* W1s, const float* W1d,
                             const float* W2s, const float* W2d,
                             const float* W3s, const float* W3d,
                             unsigned short* P1s, unsigned short* P1d,
                             unsigned short* P2s, unsigned short* P2d,
                             unsigned short* P3s, unsigned short* P3d) {
    int b = blockIdx.x;
    if (b < EBL) {
        int e = b * 256 + threadIdx.x;
        if (e < EE) atomicAdd(&counts[dst[e]], 1);
        return;
    }
    int idx = (b - EBL) * 256 + threadIdx.x;
    if (idx < IDS128) { pack_one(W1s, P1s, idx, 4); return; }
    idx -= IDS128;
    if (idx < IDS128) { pack_one(W1d, P1d, idx, 4); return; }
    idx -= IDS128;
    if (idx < IDS192) { pack_one(W2s, P2s, idx, 6); return; }
    idx -= IDS192;
    if (idx < IDS192) { pack_one(W2d, P2d, idx, 6); return; }
    idx -= IDS192;
    if (idx < IDS192) { pack_one(W3s, P3s, idx, 6); return; }
    idx -= IDS192;
    if (idx < IDS192) { pack_one(W3d, P3d, idx, 6); return; }
}

// ---------------- block scan: wave-shuffle version ----------------
__global__ void k_scan_block(const int* __restrict__ in, int* __restrict__ out,
                             int* __restrict__ bsums) {
    int tid = threadIdx.x;
    int lane = tid & 63, w = tid >> 6;          // 16 waves
    int i = blockIdx.x * 1024 + tid;
    int v = (i < NN) ? in[i] : 0;
    int s = v;
#pragma unroll
    for (int d = 1; d < 64; d <<= 1) {
        int t = __shfl_up(s, d, 64);
        if (lane >= d) s += t;                  // s = inclusive wave scan
    }
    __shared__ int wsum[16], wpre[16];
    if (lane == 63) wsum[w] = s;
    __syncthreads();
    if (w == 0 && lane < 16) {
        int x = wsum[lane];
#pragma unroll
        for (int d = 1; d < 16; d <<= 1) {
            int t = __shfl_up(x, d, 64);
            if (lane >= d) x += t;
        }
        wpre[lane] = x - wsum[lane];            // exclusive prefix of wave sums
        if (lane == 15) bsums[blockIdx.x] = x;  // block total
    }
    __syncthreads();
    if (i < NN) out[i] = s - v + wpre[w];       // exclusive scan
}

// fused: each block computes its own bsums-prefix (nb <= 64) then adds it
__global__ void k_scan_add(int* __restrict__ row_ptr, const int* __restrict__ bsums, int nb) {
    __shared__ int sbase;
    int tid = threadIdx.x;
    if (tid < 64) {
        int v = (tid < blockIdx.x) ? bsums[tid] : 0;   // blockIdx.x <= nb <= 64
        v = wsumi(v);
        if (tid == 0) sbase = v;
    }
    __syncthreads();
    int i = blockIdx.x * 1024 + tid;
    if (i < NN) row_ptr[i] += sbase;
    else if (i == NN) row_ptr[NN] = EE;   // sentinel for node-centric kernel
}

__global__ void k_scatter(const int* __restrict__ src, const int* __restrict__ dst,
                          const int* __restrict__ row_ptr, int* __restrict__ cursor,
                          int* __restrict__ csr_src) {
    int e = blockIdx.x * 256 + threadIdx.x;
    if (e >= EE) return;
    int v = dst[e];
    int pos = row_ptr[v] + atomicAdd(&cursor[v], 1);
    csr_src[pos] = src[e];
}

// ---------------- MFMA GEMM: [N,K]@[K,192] x2 (Ws,Wd); outputs bf16 ------------
// R25 two-pass slim build. Epilogue keeps the LDS transpose (R6/R7 rule: HBM
// writeback clean only with >=128B adjacent-lane contiguous runs).
template <int K, bool BF16IN>
__global__ __launch_bounds__(256, 4) void k_gemm_mfma(const void* __restrict__ Xin,
                                                      const unsigned short* __restrict__ WPs,
                                                      const unsigned short* __restrict__ WPd,
                                                      unsigned short* __restrict__ FS,
                                                      unsigned short* __restrict__ FD) {
    constexpr int Kc = K / 32;
    constexpr int XW = K + 8;                      // xs row width (shorts)
    constexpr int BW = (XW > 200) ? XW : 200;      // union width (200 for K<=192)
    __shared__ unsigned short smem[64 * BW];       // 25.6 KB
    unsigned short (*xs)[XW]  = (unsigned short (*)[XW])smem;
    unsigned short (*cs)[200] = (unsigned short (*)[200])smem;
    int tid = threadIdx.x;
    int row0 = blockIdx.x * 64;
    int lane = tid & 63, wv = tid >> 6;
    int m = lane & 15, quad = lane >> 4;

    const unsigned short* WPx[2] = {WPs, WPd};
    unsigned short* OUTx[2] = {FS, FD};

    for (int half = 0; half < 2; half++) {
        // ---- stage X tile (re-staged on pass 1; L2-hot) ----
        if (BF16IN) {
            const unsigned short* XB = (const unsigned short*)Xin;
            for (int c = tid; c < 64 * K / 8; c += 256) {
                int r = c / (K / 8), kk = (c - r * (K / 8)) * 8;
                int row = row0 + r; if (row > NN - 1) row = NN - 1;   // clamp (loads only)
                *(bf16x8*)&xs[r][kk] = *(const bf16x8*)&XB[(unsigned)(row * K + kk)];
            }
        } else {
            const float* X = (const float*)Xin;
            for (int c = tid; c < 64 * K / 4; c += 256) {
                int r = c / (K / 4), k4 = (c - r * (K / 4)) * 4;
                int row = row0 + r; if (row > NN - 1) row = NN - 1;
                f32x4 v = *(const f32x4*)&X[(unsigned)(row * K + k4)];
                xs[r][k4 + 0] = f2bf(v[0]);
                xs[r][k4 + 1] = f2bf(v[1]);
                xs[r][k4 + 2] = f2bf(v[2]);
                xs[r][k4 + 3] = f2bf(v[3]);
            }
        }
        __syncthreads();

        // ---- kc loop: this pass's 12 column-tiles (3 per wave) ----
        f32x4 acc[4][3];
#pragma unroll
        for (int s = 0; s < 4; s++)
#pragma unroll
            for (int t = 0; t < 3; t++) acc[s][t] = (f32x4){0.f, 0.f, 0.f, 0.f};

        const unsigned short* wp = WPx[half];
        for (int kc = 0; kc < Kc; kc++) {
            bf16x8 b[3];
#pragma unroll
            for (int t = 0; t < 3; t++) {
                int c = wv * 3 + t;                // 0..11
                b[t] = *(const bf16x8*)&wp[(unsigned)(((c * Kc + kc) * 64 + lane) * 8)];
            }
#pragma unroll
            for (int s = 0; s < 4; s++) {
                bf16x8 a = *(const bf16x8*)&xs[s * 16 + m][kc * 32 + quad * 8];
#pragma unroll
                for (int t = 0; t < 3; t++)
                    acc[s][t] = __builtin_amdgcn_mfma_f32_16x16x32_bf16(a, b[t], acc[s][t], 0, 0, 0);
            }
        }
        __syncthreads();    // xs reads done before cs overwrite (shared buffer)

        // ---- LDS transpose + vector store (192 cols of this pass's matrix) ----
#pragma unroll
        for (int s = 0; s < 4; s++)
#pragma unroll
            for (int t = 0; t < 3; t++) {
                int ct = wv * 3 + t;
#pragma unroll
                for (int r = 0; r < 4; r++)
                    cs[s * 16 + quad * 4 + r][ct * 16 + m] = f2bf(acc[s][t][r]);
            }
        __syncthreads();
        unsigned short* OUT = OUTx[half];
#pragma unroll
        for (int it = 0; it < 6; it++) {
            int c = tid + it * 256;                // 0..1535
            int row = c / 24, ch = c - row * 24;
            int grow = row0 + row;
            if (grow < NN)
                *(bf16x8*)&OUT[(unsigned)(grow * HD + ch * 8)] =
                    *(const bf16x8*)&cs[row][ch * 8];
        }
        __syncthreads();    // cs reads done before next pass's stage overwrites
    }
}

// ---------------- node-centric GATv2 (CSR), 16-lane group per node -------------
// R20: group = node, index order (locality!), 3-deep software pipeline.
// R10 lesson: degree-sorted reordering destroys FD/XB locality and its
// counting-sort build serializes on 64 atomic cursors -- do not reorder.
// FINAL=false: store finalized bf16 next-GEMM input (r/den + bias), [NN][192].
// FINAL=true : store head-mean (1/3 * sum_h (r/den + bias)) f32, [NN][64].
template <bool FINAL>
__global__ __launch_bounds__(256) void k_node_gat(const int* __restrict__ row_ptr,
                                                  const int* __restrict__ csr_src,
                                                  const unsigned short* __restrict__ FS,
                                                  const unsigned short* __restrict__ FD,
                                                  const float* __restrict__ A,
                                                  const float* __restrict__ Bv,
                                                  unsigned short* __restrict__ XB,
                                                  float* __restrict__ H64) {
    int tid = threadIdx.x;
    int grp = tid >> 4, sub = tid & 15;         // 16 groups per block
    int node = blockIdx.x * 16 + grp;           // grid exact: 3125*16 = 50000
    int col = sub * 4;

    float a[3][4];
#pragma unroll
    for (int h = 0; h < 3; h++) {
        f32x4 av = *(const f32x4*)&A[h * 64 + col];
#pragma unroll
        for (int j = 0; j < 4; j++) a[h][j] = av[j];
    }

    int lo = row_ptr[node], hi = row_ptr[node + 1];

    float g[3][4];
#pragma unroll
    for (int h = 0; h < 3; h++) load4(&FD[(size_t)node * HD + h * 64 + col], g[h]);

    float r[3][4];
#pragma unroll
    for (int h = 0; h < 3; h++)
#pragma unroll
        for (int j = 0; j < 4; j++) r[h][j] = 0.f;
    float d0 = 0.f, d1 = 0.f, d2 = 0.f;

    auto accum = [&](const float f[3][4]) {
        float p0 = 0.f, p1 = 0.f, p2 = 0.f;
#pragma unroll
        for (int j = 0; j < 4; j++) {
            float s0 = f[0][j] + g[0][j]; s0 = fmaxf(s0, 0.2f * s0); p0 += s0 * a[0][j];
            float s1 = f[1][j] + g[1][j]; s1 = fmaxf(s1, 0.2f * s1); p1 += s1 * a[1][j];
            float s2 = f[2][j] + g[2][j]; s2 = fmaxf(s2, 0.2f * s2); p2 += s2 * a[2][j];
        }
        // 4-step butterfly within the 16-lane group (masks < 16 stay in-group)
#pragma unroll
        for (int m = 8; m > 0; m >>= 1) {
            p0 += __shfl_xor(p0, m, 64);
            p1 += __shfl_xor(p1, m, 64);
            p2 += __shfl_xor(p2, m, 64);
        }
        float w0 = __expf(p0), w1 = __expf(p1), w2 = __expf(p2);
#pragma unroll
        for (int j = 0; j < 4; j++) {
            r[0][j] += w0 * f[0][j];
            r[1][j] += w1 * f[1][j];
            r[2][j] += w2 * f[2][j];
        }
        d0 += w0; d1 += w1; d2 += w2;
    };

    if (hi > lo) {
        int last = hi - 1;
        float fA[3][4], fB[3][4], fC[3][4];
        loadrow(FS, csr_src[lo], col, fA);
        loadrow(FS, csr_src[lo + 1 <= last ? lo + 1 : last], col, fB);
        for (int e = lo; e < hi; e += 3) {
            // prefetch the index stream for this step up front (independent loads)
            int eC = e + 2 <= last ? e + 2 : last;
            int eA = e + 3 <= last ? e + 3 : last;
            int eB = e + 4 <= last ? e + 4 : last;
            int uC = csr_src[eC], uA = csr_src[eA], uB = csr_src[eB];
            loadrow(FS, uC, col, fC);      // in flight during accum(fA), accum(fB)
            accum(fA);                     // edge e (always valid inside loop)
            loadrow(FS, uA, col, fA);      // for e+3, in flight 2 phases
            if (e + 1 < hi) accum(fB);
            loadrow(FS, uB, col, fB);      // for e+4, in flight 2 phases
            if (e + 2 < hi) accum(fC);
        }
    }

    float b[3][4];
#pragma unroll
    for (int h = 0; h < 3; h++) {
        f32x4 bv = *(const f32x4*)&Bv[h * 64 + col];
#pragma unroll
        for (int j = 0; j < 4; j++) b[h][j] = bv[j];
    }

    float q0 = fmaxf(d0, 1e-9f), q1 = fmaxf(d1, 1e-9f), q2 = fmaxf(d2, 1e-9f);
    if (FINAL) {
        f32x4 m;
#pragma unroll
        for (int j = 0; j < 4; j++)
            m[j] = (r[0][j] / q0 + b[0][j] + r[1][j] / q1 + b[1][j] +
                    r[2][j] / q2 + b[2][j]) * (1.f / 3.f);
        *(f32x4*)&H64[(size_t)node * 64 + col] = m;
    } else {
        float qq[3] = {q0, q1, q2};
#pragma unroll
        for (int h = 0; h < 3; h++) {
            unsigned short o0 = f2bf(r[h][0] / qq[h] + b[h][0]);
            unsigned short o1 = f2bf(r[h][1] / qq[h] + b[h][1]);
            unsigned short o2 = f2bf(r[h][2] / qq[h] + b[h][2]);
            unsigned short o3 = f2bf(r[h][3] / qq[h] + b[h][3]);
            u32x2 w;
            w[0] = (unsigned)o0 | ((unsigned)o1 << 16);
            w[1] = (unsigned)o2 | ((unsigned)o3 << 16);
            *(u32x2*)&XB[(size_t)node * HD + h * 64 + col] = w;
        }
    }
}

// ---------------- final: per-graph mean (256 blocks = 4 per graph) -------------
// Layer-3 output H64 is already finalized (den, bias, head-mean applied).
__global__ __launch_bounds__(256) void k_graph_mean(const float* __restrict__ H64,
                                                    const int* __restrict__ gids,
                                                    float* __restrict__ gsum,
                                                    int* __restrict__ gcnt) {
    int g = blockIdx.x >> 2, q = blockIdx.x & 3;
    int lo, hi;
    {
        int a = 0, b = NN;
        while (a < b) { int m = (a + b) >> 1; if (gids[m] < g) a = m + 1; else b = m; }
        lo = a;
        b = NN;
        while (a < b) { int m = (a + b) >> 1; if (gids[m] < g + 1) a = m + 1; else b = m; }
        hi = a;
    }
    int len = hi - lo;
    int qlen = (len + 3) >> 2;
    int s = lo + q * qlen;
    int e = s + qlen; if (e > hi) e = hi;
    int lane = threadIdx.x & 63, wv = threadIdx.x >> 6;

    float acc = 0.f;
    for (int v = s + wv; v < e; v += 4)
        acc += H64[(size_t)v * 64 + lane];
    __shared__ float red[4][64];
    red[wv][lane] = acc;
    __syncthreads();
    if (wv == 0) {
        float t = red[0][lane] + red[1][lane] + red[2][lane] + red[3][lane];
        if (e > s) {
            atomicAdd(&gsum[g * 64 + lane], t);
            if (lane == 0) atomicAdd(&gcnt[g], e - s);
        }
    }
}

// ---------------- head: one block PER GRAPH (64 blocks) ----------------
__global__ __launch_bounds__(128) void k_head(const float* __restrict__ gsum, const int* __restrict__ gcnt,
                                              const float* __restrict__ p1, const float* __restrict__ p2,
                                              const float* __restrict__ p3,
                                              const float* __restrict__ Wex, const float* __restrict__ bex,
                                              const float* __restrict__ Wpat, const float* __restrict__ bpat,
                                              const float* __restrict__ Wc1, const float* __restrict__ bc1,
                                              const float* __restrict__ Wc2, const float* __restrict__ bc2,
                                              const float* __restrict__ Wc3, const float* __restrict__ bc3,
                                              float* __restrict__ out) {
    int g = blockIdx.x;
    int tid = threadIdx.x;
    __shared__ float pbuf[192];   // p1|p2|p3 row for this graph
    __shared__ float ex[96], xc[128], t1[64], t2[32];

    if (tid < 64)       pbuf[tid] = p1[g * 64 + tid];
    else if (tid < 128) pbuf[tid] = p2[g * 64 + tid - 64];
    if (tid < 64)       pbuf[128 + tid] = p3[g * 64 + tid];
    if (tid >= 64 && tid < 128)
        xc[tid - 64] = gsum[g * 64 + tid - 64] / fmaxf((float)gcnt[g], 1.f);
    __syncthreads();
    if (tid < 96) {
        int jj = tid & 31;
        const float* pp = &pbuf[(tid >> 5) * 64];
        float acc = bex[jj];
        for (int k = 0; k < 64; k++) acc += pp[k] * Wex[k * 32 + jj];
        ex[tid] = acc;
    }
    __syncthreads();
    if (tid < 64) {
        float acc = bpat[tid];
        for (int k = 0; k < 96; k++) acc += ex[k] * Wpat[k * 64 + tid];
        xc[64 + tid] = acc > 0.f ? acc : 0.01f * acc;
    }
    __syncthreads();
    if (tid < 64) {
        float acc = bc1[tid];
        for (int k = 0; k < 128; k++) acc += xc[k] * Wc1[k * 64 + tid];
        t1[tid] = acc > 0.f ? acc : 0.01f * acc;
    }
    __syncthreads();
    if (tid < 32) {
        float acc = bc2[tid];
        for (int k = 0; k < 64; k++) acc += t1[k] * Wc2[k * 32 + tid];
        t2[tid] = acc > 0.f ? acc : 0.01f * acc;
    }
    __syncthreads();
    if (tid < 2) {
        float acc = bc3[tid];
        for (int k = 0; k < 32; k++) acc += t2[k] * Wc3[k * 2 + tid];
        out[g * 2 + tid] = acc;
    }
}

extern "C" void kernel_launch(void* const* d_in, const int* in_sizes, int n_in,
                              void* d_out, int out_size, void* d_ws, size_t ws_size,
                              hipStream_t stream) {
    const float* X0  = (const float*)d_in[0];
    const int*   src = (const int*)d_in[1];
    const int*   dst = (const int*)d_in[2];
    const int*   gid = (const int*)d_in[3];
    const float* p1  = (const float*)d_in[4];
    const float* p2  = (const float*)d_in[5];
    const float* p3  = (const float*)d_in[6];
    const float* W1s = (const float*)d_in[7],  *W1d = (const float*)d_in[8];
    const float* a1  = (const float*)d_in[9],  *b1  = (const float*)d_in[10];
    const float* W2s = (const float*)d_in[11], *W2d = (const float*)d_in[12];
    const float* a2  = (const float*)d_in[13], *b2  = (const float*)d_in[14];
    const float* W3s = (const float*)d_in[15], *W3d = (const float*)d_in[16];
    const float* a3  = (const float*)d_in[17], *b3  = (const float*)d_in[18];
    const float* Wex = (const float*)d_in[19], *bex = (const float*)d_in[20];
    const float* Wpat= (const float*)d_in[21], *bpat= (const float*)d_in[22];
    const float* Wc1 = (const float*)d_in[23], *bc1 = (const float*)d_in[24];
    const float* Wc2 = (const float*)d_in[25], *bc2 = (const float*)d_in[26];
    const float* Wc3 = (const float*)d_in[27], *bc3 = (const float*)d_in[28];
    float* out = (float*)d_out;

    char* ws = (char*)d_ws;
    size_t off = 0;
    auto alloc = [&](size_t bytes) -> char* {
        char* p = ws + off;
        off = (off + bytes + 255) & ~(size_t)255;
        return p;
    };
    unsigned short* FS = (unsigned short*)alloc((size_t)NN * HD * 2);  // bf16
    unsigned short* FD = (unsigned short*)alloc((size_t)NN * HD * 2);  // bf16
    unsigned short* XB = (unsigned short*)alloc((size_t)NN * HD * 2);  // bf16 inter-layer
    float*          H64= (float*)alloc((size_t)NN * 64 * 4);           // layer-3 head-mean
    unsigned short* P1s = (unsigned short*)alloc((size_t)192 * 192 * 2);
    unsigned short* P1d = (unsigned short*)alloc((size_t)192 * 192 * 2);
    unsigned short* P2s = (unsigned short*)alloc((size_t)192 * 192 * 2);
    unsigned short* P2d = (unsigned short*)alloc((size_t)192 * 192 * 2);
    unsigned short* P3s = (unsigned short*)alloc((size_t)192 * 192 * 2);
    unsigned short* P3d = (unsigned short*)alloc((size_t)192 * 192 * 2);
    int* row_ptr = (int*)alloc((size_t)(NN + 1) * 4);
    int* csr_src = (int*)alloc((size_t)EE * 4);
    int* bsums   = (int*)alloc(64 * 4);
    // zeroed region (ONE memset): counts | cursor | gsum | gcnt  (~0.4 MB)
    char* zbase = ws + off;
    int*   counts = (int*)alloc((size_t)NN * 4);
    int*   cursor = (int*)alloc((size_t)NN * 4);
    float* gsum   = (float*)alloc((size_t)GG * 64 * 4);
    int*   gcnt   = (int*)alloc((size_t)GG * 4);
    size_t zbytes = (size_t)((ws + off) - zbase);

    hipMemsetAsync(zbase, 0, zbytes, stream);

    int nb  = (NN + 1023) / 1024;
    {
        int packbl = (2 * IDS128 + 4 * IDS192 + 255) / 256;   // 96
        k_count_pack<<<EBL + packbl, 256, 0, stream>>>(dst, counts,
                                                       W1s, W1d, W2s, W2d, W3s, W3d,
                                                       P1s, P1d, P2s, P2d, P3s, P3d);
    }
    k_scan_block<<<nb, 1024, 0, stream>>>(counts, row_ptr, bsums);
    k_scan_add<<<nb, 1024, 0, stream>>>(row_ptr, bsums, nb);
    k_scatter<<<EBL, 256, 0, stream>>>(src, dst, row_ptr, cursor, csr_src);

    int gblk = (NN + 63) / 64;          // 782 blocks, 64 rows each
    int nblk = NN / 16;                 // 3125 node blocks (16 groups each)

    // layer 1 (K = 128, float input)
    k_gemm_mfma<128, false><<<gblk, 256, 0, stream>>>(X0, P1s, P1d, FS, FD);
    k_node_gat<false><<<nblk, 256, 0, stream>>>(row_ptr, csr_src, FS, FD, a1, b1, XB, nullptr);
    // layer 2 (K = 192, bf16 finalized input)
    k_gemm_mfma<192, true><<<gblk, 256, 0, stream>>>(XB, P2s, P2d, FS, FD);
    k_node_gat<false><<<nblk, 256, 0, stream>>>(row_ptr, csr_src, FS, FD, a2, b2, XB, nullptr);
    // layer 3 (K = 192, bf16 finalized input)
    k_gemm_mfma<192, true><<<gblk, 256, 0, stream>>>(XB, P3s, P3d, FS, FD);
    k_node_gat<true><<<nblk, 256, 0, stream>>>(row_ptr, csr_src, FS, FD, a3, b3, nullptr, H64);

    // per-graph mean (256 blocks) then head (64 blocks)
    k_graph_mean<<<GG * 4, 256, 0, stream>>>(H64, gid, gsum, gcnt);
    k_head<<<GG, 128, 0, stream>>>(gsum, gcnt, p1, p2, p3, Wex, bex, Wpat, bpat,
                                   Wc1, bc1, Wc2, bc2, Wc3, bc3, out);
}